// Round 2
// baseline (462.155 us; speedup 1.0000x reference)
//
#include <hip/hip_runtime.h>
#include <math.h>

// Problem constants (from reference): D=2048, E=8, T=32768, top_k=2
constexpr int D_DIM = 2048;
constexpr int NEXP  = 8;
constexpr int NTOK  = 32768;
constexpr int TT    = 4;             // tokens per wave
constexpr int KC    = 128;           // k rows per chunk: 32 kg x 4 rows
constexpr int NCH   = D_DIM / KC;    // 16 chunks
constexpr int WPB   = 4;             // waves per block (256 threads)

typedef float vf4 __attribute__((ext_vector_type(4)));

__device__ __forceinline__ float softplus_f(float x) {
    return (x > 20.0f) ? x : log1pf(expf(x));
}

// No LDS, no barriers: each lane's W slice (rows 4kg..4kg+3, all 8 experts) is
// 32 CONTIGUOUS floats in row-major W -> 8 aligned float4 global loads per chunk.
// W is 128 KiB total -> L2-resident on every XCD; the 64B lines at kg*128 are
// L1-reused across the 8 loads. Full unroll over chunks lets the scheduler
// software-pipeline h (HBM stream) and W (L1/L2) loads under the FMA stream
// with no barrier-forced vmcnt(0) drains.
__global__ __launch_bounds__(256, 4)
void noisy_topk_router(const float* __restrict__ h,
                       const float* __restrict__ Ww,
                       const float* __restrict__ bw,
                       const float* __restrict__ Wn,
                       const float* __restrict__ bn,
                       const float* __restrict__ eps,
                       float* __restrict__ out_sparse,
                       float* __restrict__ out_ix,
                       float* __restrict__ out_full)
{
    const int tid  = threadIdx.x;
    const int lane = tid & 63;
    const int wave = tid >> 6;
    const int t0   = (blockIdx.x * WPB + wave) * TT;
    const int role = lane & 1;       // 0 -> W_w, 1 -> W_n
    const int kg   = lane >> 1;      // owns rows 4kg..4kg+3 within each chunk

    const float* Wm    = role ? Wn : Ww;
    const float* wbase = Wm + kg * 32;                         // rows 4kg..4kg+3; +1024 floats/chunk
    const float* hbase = h + (size_t)t0 * D_DIM + 4 * kg;

    // p[t*8+o]: partial dot for (token t0+t, expert o of this lane's matrix)
    float p[TT * 8];
#pragma unroll
    for (int i = 0; i < TT * 8; ++i) p[i] = 0.0f;

#pragma unroll
    for (int c = 0; c < NCH; ++c) {
        // this lane's W slice for chunk c: 32 contiguous floats (4 rows x 8 experts)
        vf4 wv[8];
#pragma unroll
        for (int q = 0; q < 8; ++q)
            wv[q] = *(const vf4*)(wbase + c * (KC * NEXP) + q * 4);

        // h for the TT tokens, this chunk's 4 rows owned by this lane
        vf4 hv[TT];
#pragma unroll
        for (int t = 0; t < TT; ++t)
            hv[t] = *(const vf4*)(hbase + (size_t)t * D_DIM + c * KC);

#pragma unroll
        for (int t = 0; t < TT; ++t) {
#pragma unroll
            for (int r = 0; r < 4; ++r) {
                const float x = hv[t][r];
#pragma unroll
                for (int o = 0; o < 8; ++o) {
                    const int j = r * 8 + o;
                    p[t * 8 + o] = fmaf(x, wv[j >> 2][j & 3], p[t * 8 + o]);
                }
            }
        }
    }

    // Compacting reduce-scatter over the 32 k-groups (lane bits 1..5; bit 0 = role).
    // After 5 steps lane L holds p[0] = value t*8+o (t = L>>4, o = (L>>1)&7) for matrix L&1.
#pragma unroll
    for (int s = 0; s < 5; ++s) {
        const int m = 2 << s;
        const bool hi = (lane & m) != 0;
        const int n = 32 >> (s + 1);
#pragma unroll
        for (int j = 0; j < n; ++j) {
            float a  = p[2 * j];
            float b  = p[2 * j + 1];
            float ta = __shfl_xor(a, m, 64);
            float tb = __shfl_xor(b, m, 64);
            p[j] = hi ? (b + tb) : (a + ta);
        }
    }

    // Epilogue: lane L -> token t0 + (L>>4), expert o = (L>>1)&7, matrix = L&1.
    const int  o         = (lane >> 1) & 7;
    const bool noiseLane = (role != 0);
    const int  tok       = t0 + (lane >> 4);
    const float bias     = noiseLane ? bn[o] : bw[o];

    const float val = p[0] + bias;              // logit (role 0) or noise-logit (role 1)
    const float sp  = softplus_f(val);
    const float spN = __shfl_xor(sp, 1, 64);    // logit lane <- partner's softplus
    const float ev  = eps[(size_t)tok * NEXP + o];
    const float noisy = val + ev * spN;         // meaningful on logit lanes

    // argmax over the 8 logit lanes (same token, role 0): masks {2,4,8}
    float v0 = noisy; int i0 = o;
#pragma unroll
    for (int m = 2; m <= 8; m <<= 1) {
        float ov = __shfl_xor(v0, m, 64);
        int   oi = __shfl_xor(i0, m, 64);
        bool take = (ov > v0) || (ov == v0 && oi < i0);
        v0 = take ? ov : v0;
        i0 = take ? oi : i0;
    }
    // second argmax (exclude i0)
    float v1 = (o == i0) ? -INFINITY : noisy; int i1 = o;
#pragma unroll
    for (int m = 2; m <= 8; m <<= 1) {
        float ov = __shfl_xor(v1, m, 64);
        int   oi = __shfl_xor(i1, m, 64);
        bool take = (ov > v1) || (ov == v1 && oi < i1);
        v1 = take ? ov : v1;
        i1 = take ? oi : i1;
    }
    // full softmax over 8 experts
    const float ex = expf(noisy - v0);
    float ssum = ex;
#pragma unroll
    for (int m = 2; m <= 8; m <<= 1) ssum += __shfl_xor(ssum, m, 64);
    const float fullv = ex / ssum;
    // sparse softmax over the top-2 (others exactly 0)
    const float dd  = expf(v1 - v0);
    const float den = 1.0f + dd;
    const float sparsev = (o == i0) ? (1.0f / den)
                        : (o == i1) ? (dd / den) : 0.0f;

    if (!noiseLane) {
        out_sparse[(size_t)tok * NEXP + o] = sparsev;
        out_full  [(size_t)tok * NEXP + o] = fullv;
        if (o == 0) {
            out_ix[(size_t)tok * 2]     = (float)i0;
            out_ix[(size_t)tok * 2 + 1] = (float)i1;
        }
    }
}

extern "C" void kernel_launch(void* const* d_in, const int* in_sizes, int n_in,
                              void* d_out, int out_size, void* d_ws, size_t ws_size,
                              hipStream_t stream) {
    const float* h   = (const float*)d_in[0];
    const float* Ww  = (const float*)d_in[1];
    const float* bw  = (const float*)d_in[2];
    const float* Wn  = (const float*)d_in[3];
    const float* bn  = (const float*)d_in[4];
    const float* eps = (const float*)d_in[5];
    // d_in[6] = top_k (always 2 for this problem)

    float* out_sparse = (float*)d_out;                         // [T, 8]
    float* out_ix     = out_sparse + (size_t)NTOK * NEXP;      // [T, 2] (as float)
    float* out_full   = out_ix + (size_t)NTOK * 2;             // [T, 8]

    const int grid = NTOK / (TT * WPB);  // 2048 blocks x 256 threads
    noisy_topk_router<<<grid, 256, 0, stream>>>(h, Ww, bw, Wn, bn, eps,
                                                out_sparse, out_ix, out_full);
}

// Round 4
// 397.036 us; speedup vs baseline: 1.1640x; 1.1640x over previous
//
#include <hip/hip_runtime.h>
#include <math.h>

// Problem constants: D=2048, E=8, T=32768, top_k=2
constexpr int D_DIM = 2048;
constexpr int NEXP  = 8;
constexpr int NTOK  = 32768;
constexpr int TT    = 4;             // tokens per wave
constexpr int KC    = 128;           // rows per chunk: 32 kg x 4 rows
constexpr int NCH   = D_DIM / KC;    // 16 chunks
constexpr int WAVES = 16;            // waves per block
constexpr int BLKT  = WAVES * 64;    // 1024 threads

typedef float vf4 __attribute__((ext_vector_type(4)));

__device__ __forceinline__ float softplus_f(float x) {
    return (x > 20.0f) ? x : log1pf(expf(x));
}

// Structure: W (both matrices) staged into LDS in TWO 64 KiB halves -> only 3
// barriers in the whole kernel (vs 32 in the per-chunk double-buffer version).
// Main loop has ZERO barriers: h streams from HBM with distance-1 register
// prefetch and the compiler keeps loads in flight across chunks (no forced
// vmcnt(0) drains). LDS layout is XOR-swizzled float4s: slice float4 f of
// row-group b, matrix m lives at sW4[b*16 + m*8 + (f ^ (b&7))] -> ds_read_b128
// at the 32-bank floor (8 lanes per 4-bank group for a 1 KiB wave read).
__global__ __launch_bounds__(1024, 4)
void noisy_topk_router(const float* __restrict__ h,
                       const float* __restrict__ Ww,
                       const float* __restrict__ bw,
                       const float* __restrict__ Wn,
                       const float* __restrict__ bn,
                       const float* __restrict__ eps,
                       float* __restrict__ out_sparse,
                       float* __restrict__ out_ix,
                       float* __restrict__ out_full)
{
    __shared__ vf4 sW4[4096];        // 64 KiB: one half (1024 rows) of Ww+Wn

    const int tid  = threadIdx.x;
    const int lane = tid & 63;
    const int wave = tid >> 6;
    const int t0   = (blockIdx.x * WAVES + wave) * TT;
    const int role = lane & 1;       // 0 -> W_w, 1 -> W_n
    const int kg2  = lane >> 1;      // owns rows 4*kg2..4*kg2+3 within each chunk
    const int s7   = kg2 & 7;

    const float* hbase = h + (size_t)t0 * D_DIM + 4 * kg2;

    // Stage half hh (rows hh*1024 .. hh*1024+1023 of both matrices) into LDS.
    // 4096 float4s, 4 per thread. mat uniform per wave (idx>>11 constant).
    auto stage = [&](int hh) {
#pragma unroll
        for (int it = 0; it < 4; ++it) {
            const int idx = it * BLKT + tid;        // 0..4095
            const int mat = idx >> 11;              // 0: Ww, 1: Wn
            const int gfi = idx & 2047;             // float4 idx within matrix half
            const float* src = (mat ? Wn : Ww) + (size_t)hh * 8192 + (size_t)gfi * 4;
            vf4 v = *(const vf4*)src;
            const int b = gfi >> 3;                              // local row-group
            const int f = ((gfi >> 1) & 3) * 2 + (idx & 1);      // slice float4 idx
            sW4[b * 16 + mat * 8 + (f ^ (b & 7))] = v;
        }
    };

    // p[t*8+o]: partial dot for (token t0+t, expert o of this lane's matrix)
    float p[TT * 8];
#pragma unroll
    for (int i = 0; i < TT * 8; ++i) p[i] = 0.0f;

    stage(0);
    vf4 hv[TT];
#pragma unroll
    for (int t = 0; t < TT; ++t)
        hv[t] = *(const vf4*)(hbase + (size_t)t * D_DIM);
    __syncthreads();

#pragma unroll
    for (int c = 0; c < NCH; ++c) {
        if (c == 8) {                // swap in second half of W (only barriers in loop)
            __syncthreads();
            stage(1);
            __syncthreads();
        }
        const int cc = c & 7;
        const int A0 = (cc * 32 + kg2) * 16 + role * 8 + s7;

        // this lane's W slice: 8 float4 (4 rows x 8 experts), swizzle-corrected
        vf4 wv[8];
#pragma unroll
        for (int q = 0; q < 8; ++q)
            wv[q] = sW4[A0 ^ q];

        // distance-1 prefetch of next chunk's h (no barrier -> stays in flight)
        vf4 hvn[TT];
        if (c + 1 < NCH) {
#pragma unroll
            for (int t = 0; t < TT; ++t)
                hvn[t] = *(const vf4*)(hbase + (size_t)t * D_DIM + (c + 1) * KC);
        }

#pragma unroll
        for (int t = 0; t < TT; ++t) {
#pragma unroll
            for (int r = 0; r < 4; ++r) {
                const float x = hv[t][r];
#pragma unroll
                for (int o = 0; o < 8; ++o) {
                    const int j = r * 8 + o;
                    p[t * 8 + o] = fmaf(x, wv[j >> 2][j & 3], p[t * 8 + o]);
                }
            }
        }

        if (c + 1 < NCH) {
#pragma unroll
            for (int t = 0; t < TT; ++t) hv[t] = hvn[t];
        }
    }

    // Compacting reduce-scatter over the 32 k-groups (lane bits 1..5; bit 0 = role).
    // After 5 steps lane L holds p[0] = value t*8+o (t = L>>4, o = (L>>1)&7) for matrix L&1.
#pragma unroll
    for (int s = 0; s < 5; ++s) {
        const int m = 2 << s;
        const bool hi = (lane & m) != 0;
        const int n = 32 >> (s + 1);
#pragma unroll
        for (int j = 0; j < n; ++j) {
            float a  = p[2 * j];
            float b  = p[2 * j + 1];
            float ta = __shfl_xor(a, m, 64);
            float tb = __shfl_xor(b, m, 64);
            p[j] = hi ? (b + tb) : (a + ta);
        }
    }

    // Epilogue: lane L -> token t0 + (L>>4), expert o = (L>>1)&7, matrix = L&1.
    const int  o         = (lane >> 1) & 7;
    const bool noiseLane = (role != 0);
    const int  tok       = t0 + (lane >> 4);
    const float bias     = noiseLane ? bn[o] : bw[o];

    const float val = p[0] + bias;              // logit (role 0) or noise-logit (role 1)
    const float sp  = softplus_f(val);
    const float spN = __shfl_xor(sp, 1, 64);    // logit lane <- partner's softplus
    const float ev  = eps[(size_t)tok * NEXP + o];
    const float noisy = val + ev * spN;         // meaningful on logit lanes

    // argmax over the 8 logit lanes (same token, role 0): masks {2,4,8}
    float v0 = noisy; int i0 = o;
#pragma unroll
    for (int m = 2; m <= 8; m <<= 1) {
        float ov = __shfl_xor(v0, m, 64);
        int   oi = __shfl_xor(i0, m, 64);
        bool take = (ov > v0) || (ov == v0 && oi < i0);
        v0 = take ? ov : v0;
        i0 = take ? oi : i0;
    }
    // second argmax (exclude i0)
    float v1 = (o == i0) ? -INFINITY : noisy; int i1 = o;
#pragma unroll
    for (int m = 2; m <= 8; m <<= 1) {
        float ov = __shfl_xor(v1, m, 64);
        int   oi = __shfl_xor(i1, m, 64);
        bool take = (ov > v1) || (ov == v1 && oi < i1);
        v1 = take ? ov : v1;
        i1 = take ? oi : i1;
    }
    // full softmax over 8 experts
    const float ex = expf(noisy - v0);
    float ssum = ex;
#pragma unroll
    for (int m = 2; m <= 8; m <<= 1) ssum += __shfl_xor(ssum, m, 64);
    const float fullv = ex / ssum;
    // sparse softmax over the top-2 (others exactly 0)
    const float dd  = expf(v1 - v0);
    const float den = 1.0f + dd;
    const float sparsev = (o == i0) ? (1.0f / den)
                        : (o == i1) ? (dd / den) : 0.0f;

    if (!noiseLane) {
        out_sparse[(size_t)tok * NEXP + o] = sparsev;
        out_full  [(size_t)tok * NEXP + o] = fullv;
        if (o == 0) {
            out_ix[(size_t)tok * 2]     = (float)i0;
            out_ix[(size_t)tok * 2 + 1] = (float)i1;
        }
    }
}

extern "C" void kernel_launch(void* const* d_in, const int* in_sizes, int n_in,
                              void* d_out, int out_size, void* d_ws, size_t ws_size,
                              hipStream_t stream) {
    const float* h   = (const float*)d_in[0];
    const float* Ww  = (const float*)d_in[1];
    const float* bw  = (const float*)d_in[2];
    const float* Wn  = (const float*)d_in[3];
    const float* bn  = (const float*)d_in[4];
    const float* eps = (const float*)d_in[5];
    // d_in[6] = top_k (always 2 for this problem)

    float* out_sparse = (float*)d_out;                         // [T, 8]
    float* out_ix     = out_sparse + (size_t)NTOK * NEXP;      // [T, 2] (as float)
    float* out_full   = out_ix + (size_t)NTOK * 2;             // [T, 8]

    const int grid = NTOK / (WAVES * TT);  // 512 blocks x 1024 threads
    noisy_topk_router<<<grid, BLKT, 0, stream>>>(h, Ww, bw, Wn, bn, eps,
                                                 out_sparse, out_ix, out_full);
}

// Round 5
// 368.709 us; speedup vs baseline: 1.2534x; 1.0768x over previous
//
#include <hip/hip_runtime.h>
#include <math.h>

// Problem constants: D=2048, E=8, T=32768, top_k=2
constexpr int D_DIM = 2048;
constexpr int NEXP  = 8;
constexpr int NTOK  = 32768;
constexpr int TT    = 4;             // tokens per wave
constexpr int KC    = 128;           // rows per chunk: 32 kg x 4 rows
constexpr int NCH   = D_DIM / KC;    // 16 chunks
constexpr int NS    = NCH / 2;       // 8 super-chunks (2 chunks each)
constexpr int WPB   = 4;             // waves per block (256 threads)

typedef float vf4 __attribute__((ext_vector_type(4)));

__device__ __forceinline__ float softplus_f(float x) {
    return (x > 20.0f) ? x : log1pf(expf(x));
}

// Structure (r1 shape + r4 LDS layout):
//  - 256-thread blocks, 2048 blocks -> 4 INDEPENDENT blocks resident per CU
//    (cross-block overlap covers barrier stalls; r4's 16-wave lockstep block
//    proved 25% slower).
//  - W staged per SUPER-chunk (2 chunks = 256 rows, 16 KiB) into a 2-buffer
//    LDS ring -> only 8 barriers total (r1 had 16), one per super-chunk.
//  - XOR-swizzled float4 layout: slice-f4 f of (chunk cc, mat m, row-group kg)
//    stored at ((cc*2+m)*32+kg)*8 + (f ^ (kg&7)) -> ds_read_b128 / write_b128
//    at the 1KiB-per-8-cycle bank floor (r1's +1-pad forced 32x ds_read_b32).
//  - Rolling 2-vf4 W reads keep peak VGPR ~r1 level -> 4 waves/SIMD holds.
__global__ __launch_bounds__(256, 4)
void noisy_topk_router(const float* __restrict__ h,
                       const float* __restrict__ Ww,
                       const float* __restrict__ bw,
                       const float* __restrict__ Wn,
                       const float* __restrict__ bn,
                       const float* __restrict__ eps,
                       float* __restrict__ out_sparse,
                       float* __restrict__ out_ix,
                       float* __restrict__ out_full)
{
    __shared__ vf4 sW4[2 * 1024];    // 2 bufs x (2 chunks x 2 mats x 32 kg x 8 slots) = 32 KiB

    const int tid  = threadIdx.x;
    const int lane = tid & 63;
    const int wave = tid >> 6;
    const int t0   = (blockIdx.x * WPB + wave) * TT;
    const int role = lane & 1;       // 0 -> W_w, 1 -> W_n
    const int kg2  = lane >> 1;      // owns rows 4*kg2..4*kg2+3 within each chunk
    const int s7   = kg2 & 7;

    const float* hbase = h + (size_t)t0 * D_DIM + 4 * kg2;

    // Staging map: thread tid, part i (0..3): m = i>>1, gidx = (i&1)*256 + tid.
    // Source float4 (coalesced): Wm + (S*512 + gidx)*4 floats.
    // Dest slot: cc=gidx>>8, kg=(gidx>>3)&31, f=gidx&7 -> ((cc*2+m)*32+kg)*8 + (f^(kg&7)).
    int sdst[4]; const float* sptr[4];
#pragma unroll
    for (int i = 0; i < 4; ++i) {
        const int m    = i >> 1;
        const int gidx = (i & 1) * 256 + tid;
        const int cc   = gidx >> 8;
        const int kg   = (gidx >> 3) & 31;
        const int f    = gidx & 7;
        sdst[i] = ((cc * 2 + m) * 32 + kg) * 8 + (f ^ (kg & 7));
        sptr[i] = (m ? Wn : Ww) + (size_t)gidx * 4;
    }

    // p[t*8+o]: partial dot for (token t0+t, expert o of this lane's matrix)
    float p[TT * 8];
#pragma unroll
    for (int i = 0; i < TT * 8; ++i) p[i] = 0.0f;

    // ---- prologue: stage super-chunk 0 into buf 0; load h chunk 0 ----
    {
        vf4 s0 = *(const vf4*)(sptr[0]);
        vf4 s1 = *(const vf4*)(sptr[1]);
        vf4 s2 = *(const vf4*)(sptr[2]);
        vf4 s3 = *(const vf4*)(sptr[3]);
        sW4[sdst[0]] = s0;  sW4[sdst[1]] = s1;
        sW4[sdst[2]] = s2;  sW4[sdst[3]] = s3;
    }
    vf4 hv[TT];
#pragma unroll
    for (int t = 0; t < TT; ++t)
        hv[t] = *(const vf4*)(hbase + (size_t)t * D_DIM);
    __syncthreads();

    // FMA over one chunk: rolling 2-vf4 W reads (base^(2r), base^(2r+1)).
    // w[j=r*8+o] lives in vf4 2r+(o>>2), element o&3.
#define CHUNK_FMA(BASE, HV)                                                   \
    {                                                                         \
        const int base_ = (BASE);                                             \
        vf4 w0 = sW4[base_ ^ 0], w1 = sW4[base_ ^ 1];                         \
        _Pragma("unroll")                                                     \
        for (int r = 0; r < 4; ++r) {                                         \
            vf4 n0, n1;                                                       \
            if (r < 3) { n0 = sW4[base_ ^ (2*r + 2)];                         \
                         n1 = sW4[base_ ^ (2*r + 3)]; }                       \
            _Pragma("unroll")                                                 \
            for (int t = 0; t < TT; ++t) {                                    \
                const float x = (HV)[t][r];                                   \
                _Pragma("unroll")                                             \
                for (int o = 0; o < 8; ++o) {                                 \
                    const float wv = (o < 4) ? w0[o & 3] : w1[o & 3];         \
                    p[t * 8 + o] = fmaf(x, wv, p[t * 8 + o]);                 \
                }                                                             \
            }                                                                 \
            if (r < 3) { w0 = n0; w1 = n1; }                                  \
        }                                                                     \
    }

#pragma unroll
    for (int S = 0; S < NS; ++S) {
        const int  buf  = (S & 1) << 10;
        const bool more = (S + 1 < NS);
        const int  off  = (S + 1) * 2048;       // floats per matrix per super

        // issue first half of next super's W loads early (longest latency)
        vf4 s0, s1;
        if (more) {
            s0 = *(const vf4*)(sptr[0] + off);
            s1 = *(const vf4*)(sptr[1] + off);
        }
        // h for chunk 2S+1 (used in second half of this super)
        vf4 hvB[TT];
#pragma unroll
        for (int t = 0; t < TT; ++t)
            hvB[t] = *(const vf4*)(hbase + (size_t)t * D_DIM + (2*S + 1) * KC);

        // ---- chunk 2S (cc=0) ----
        CHUNK_FMA(buf + (role * 32 + kg2) * 8 + s7, hv);

        // write first half of next W; issue second half
        vf4 s2, s3;
        if (more) {
            const int ob = buf ^ 1024;
            sW4[ob + sdst[0]] = s0;
            sW4[ob + sdst[1]] = s1;
            s2 = *(const vf4*)(sptr[2] + off);
            s3 = *(const vf4*)(sptr[3] + off);
        }
        // h for chunk 2S+2 (next super's first chunk)
        vf4 hvN[TT];
        if (more) {
#pragma unroll
            for (int t = 0; t < TT; ++t)
                hvN[t] = *(const vf4*)(hbase + (size_t)t * D_DIM + (2*S + 2) * KC);
        }

        // ---- chunk 2S+1 (cc=1) ----
        CHUNK_FMA(buf + ((2 + role) * 32 + kg2) * 8 + s7, hvB);

        if (more) {
            const int ob = buf ^ 1024;
            sW4[ob + sdst[2]] = s2;
            sW4[ob + sdst[3]] = s3;
#pragma unroll
            for (int t = 0; t < TT; ++t) hv[t] = hvN[t];
            __syncthreads();                     // one barrier per super-chunk
        }
    }
#undef CHUNK_FMA

    // Compacting reduce-scatter over the 32 k-groups (lane bits 1..5; bit 0 = role).
    // After 5 steps lane L holds p[0] = value t*8+o (t = L>>4, o = (L>>1)&7) for matrix L&1.
#pragma unroll
    for (int s = 0; s < 5; ++s) {
        const int m = 2 << s;
        const bool hi = (lane & m) != 0;
        const int n = 32 >> (s + 1);
#pragma unroll
        for (int j = 0; j < n; ++j) {
            float a  = p[2 * j];
            float b  = p[2 * j + 1];
            float ta = __shfl_xor(a, m, 64);
            float tb = __shfl_xor(b, m, 64);
            p[j] = hi ? (b + tb) : (a + ta);
        }
    }

    // Epilogue: lane L -> token t0 + (L>>4), expert o = (L>>1)&7, matrix = L&1.
    const int  o         = (lane >> 1) & 7;
    const bool noiseLane = (role != 0);
    const int  tok       = t0 + (lane >> 4);
    const float bias     = noiseLane ? bn[o] : bw[o];

    const float val = p[0] + bias;              // logit (role 0) or noise-logit (role 1)
    const float sp  = softplus_f(val);
    const float spN = __shfl_xor(sp, 1, 64);    // logit lane <- partner's softplus
    const float ev  = eps[(size_t)tok * NEXP + o];
    const float noisy = val + ev * spN;         // meaningful on logit lanes

    // argmax over the 8 logit lanes (same token, role 0): masks {2,4,8}
    float v0 = noisy; int i0 = o;
#pragma unroll
    for (int m = 2; m <= 8; m <<= 1) {
        float ov = __shfl_xor(v0, m, 64);
        int   oi = __shfl_xor(i0, m, 64);
        bool take = (ov > v0) || (ov == v0 && oi < i0);
        v0 = take ? ov : v0;
        i0 = take ? oi : i0;
    }
    // second argmax (exclude i0)
    float v1 = (o == i0) ? -INFINITY : noisy; int i1 = o;
#pragma unroll
    for (int m = 2; m <= 8; m <<= 1) {
        float ov = __shfl_xor(v1, m, 64);
        int   oi = __shfl_xor(i1, m, 64);
        bool take = (ov > v1) || (ov == v1 && oi < i1);
        v1 = take ? ov : v1;
        i1 = take ? oi : i1;
    }
    // full softmax over 8 experts
    const float ex = expf(noisy - v0);
    float ssum = ex;
#pragma unroll
    for (int m = 2; m <= 8; m <<= 1) ssum += __shfl_xor(ssum, m, 64);
    const float fullv = ex / ssum;
    // sparse softmax over the top-2 (others exactly 0)
    const float dd  = expf(v1 - v0);
    const float den = 1.0f + dd;
    const float sparsev = (o == i0) ? (1.0f / den)
                        : (o == i1) ? (dd / den) : 0.0f;

    if (!noiseLane) {
        out_sparse[(size_t)tok * NEXP + o] = sparsev;
        out_full  [(size_t)tok * NEXP + o] = fullv;
        if (o == 0) {
            out_ix[(size_t)tok * 2]     = (float)i0;
            out_ix[(size_t)tok * 2 + 1] = (float)i1;
        }
    }
}

extern "C" void kernel_launch(void* const* d_in, const int* in_sizes, int n_in,
                              void* d_out, int out_size, void* d_ws, size_t ws_size,
                              hipStream_t stream) {
    const float* h   = (const float*)d_in[0];
    const float* Ww  = (const float*)d_in[1];
    const float* bw  = (const float*)d_in[2];
    const float* Wn  = (const float*)d_in[3];
    const float* bn  = (const float*)d_in[4];
    const float* eps = (const float*)d_in[5];
    // d_in[6] = top_k (always 2 for this problem)

    float* out_sparse = (float*)d_out;                         // [T, 8]
    float* out_ix     = out_sparse + (size_t)NTOK * NEXP;      // [T, 2] (as float)
    float* out_full   = out_ix + (size_t)NTOK * 2;             // [T, 8]

    const int grid = NTOK / (TT * WPB);  // 2048 blocks x 256 threads
    noisy_topk_router<<<grid, 256, 0, stream>>>(h, Ww, bw, Wn, bn, eps,
                                                out_sparse, out_ix, out_full);
}

// Round 8
// 361.104 us; speedup vs baseline: 1.2798x; 1.0211x over previous
//
#include <hip/hip_runtime.h>
#include <math.h>

// Problem constants: D=2048, E=8, T=32768, top_k=2
constexpr int D_DIM = 2048;
constexpr int NEXP  = 8;
constexpr int NTOK  = 32768;
constexpr int TT    = 2;             // tokens per wave
constexpr int SR    = 256;           // rows per super (1 KiB of one token-row)
constexpr int NS    = D_DIM / SR;    // 8 supers
constexpr int WPB   = 4;             // waves per block (256 threads)

typedef float vf4 __attribute__((ext_vector_type(4)));
typedef float vf2 __attribute__((ext_vector_type(2)));

__device__ __forceinline__ float softplus_f(float x) {
    return (x > 20.0f) ? x : log1pf(expf(x));
}

// v7: lane L owns super-rows 4L..4L+3 -> every h load is ONE clean 1 KiB
// linear wave burst (lane L takes floats 4L..4L+3), zero duplication.
// Each lane computes all 16 outputs (both matrices) for its rows; TT=2 keeps
// the accumulator set at 32 VGPRs (TT=4 needed 64 and blew the 128 cap).
// W: register-staged per super into a 2-buffer LDS ring (16 KiB/buf), one
// barrier per super. Both-sides XOR swizzle:
//   writer: slot s = k*256+tid holds W[m=(tid>>3)&1][rowgrp L=s>>4]
//           [fi=(tid&7)^((tid>>4)&7)]  (ds_write_b128 linear, conflict-free)
//   reader: lane reads slot lane*16 + (m*8 + (fi^(lane&7)))
//           (8-lane groups cover all 32 banks -> b128 floor, conflict-free)
// Reduce: 5-step compacting butterfly (32 values) + cross-half add; lanes
// 32-63 mirror lanes 0-31, epilogue (verified) runs on lanes 0-31.
__global__ __launch_bounds__(256, 4)
void noisy_topk_router(const float* __restrict__ h,
                       const float* __restrict__ Ww,
                       const float* __restrict__ bw,
                       const float* __restrict__ Wn,
                       const float* __restrict__ bn,
                       const float* __restrict__ eps,
                       float* __restrict__ out_sparse,
                       float* __restrict__ out_ix,
                       float* __restrict__ out_full)
{
    __shared__ vf4 sW4[2048];        // 2 bufs x 1024 vf4 = 32 KiB

    const int tid  = threadIdx.x;
    const int lane = tid & 63;
    const int wave = tid >> 6;
    const int t0   = (blockIdx.x * WPB + wave) * TT;
    const int role = lane & 1;
    const int s7   = lane & 7;

    const float* hbase = h + (size_t)t0 * D_DIM + 4 * lane;

    // Writer mapping (k-independent): this thread stages, for each k=0..3,
    // the vf4 at slot k*256+tid, whose content is W[wm][rowgrp k*16+(tid>>4)][wfi].
    const int    wm    = (tid >> 3) & 1;
    const int    wfi   = (tid & 7) ^ ((tid >> 4) & 7);
    const float* wbase = (wm ? Wn : Ww) + (tid >> 4) * 32 + wfi * 4;  // + k*512 + S*2048

    // p2[t*8 + m*4 + e] = partials for outputs (m, 2e) / (m, 2e+1), token t0+t
    vf2 p2[TT * 8];
#pragma unroll
    for (int i = 0; i < TT * 8; ++i) p2[i] = vf2{0.0f, 0.0f};

    vf4 hbuf[2][TT];
    vf4 sreg[4];

    // ---- prologue: W super 0 -> regs -> LDS; h super 0 -> regs ----
#pragma unroll
    for (int k = 0; k < 4; ++k) sreg[k] = *(const vf4*)(wbase + k * 512);
#pragma unroll
    for (int t = 0; t < TT; ++t) hbuf[0][t] = *(const vf4*)(hbase + (size_t)t * D_DIM);
#pragma unroll
    for (int k = 0; k < 4; ++k) sW4[k * 256 + tid] = sreg[k];
    __syncthreads();

#pragma unroll
    for (int S = 0; S < NS; ++S) {
        const int  cur  = S & 1;
        const bool more = (S + 1 < NS);

        // issue next super's loads first (deep prefetch, no barrier in between)
        if (more) {
#pragma unroll
            for (int k = 0; k < 4; ++k)
                sreg[k] = *(const vf4*)(wbase + (S + 1) * 2048 + k * 512);
#pragma unroll
            for (int t = 0; t < TT; ++t)
                hbuf[cur ^ 1][t] = *(const vf4*)(hbase + (size_t)t * D_DIM + (S + 1) * SR);
        }

        // compute: rows 4*lane..4*lane+3, all 16 outputs, TT tokens
        const int Lb = cur * 1024 + lane * 16;
#pragma unroll
        for (int r = 0; r < 4; ++r) {
#pragma unroll
            for (int m = 0; m < 2; ++m) {
                const vf4 w0 = sW4[Lb + ((m * 8 + r * 2 + 0) ^ s7)];  // outs 0-3 of row r
                const vf4 w1 = sW4[Lb + ((m * 8 + r * 2 + 1) ^ s7)];  // outs 4-7
                const vf2 w0lo = {w0[0], w0[1]}, w0hi = {w0[2], w0[3]};
                const vf2 w1lo = {w1[0], w1[1]}, w1hi = {w1[2], w1[3]};
#pragma unroll
                for (int t = 0; t < TT; ++t) {
                    const float x = hbuf[cur][t][r];
                    const vf2 xx = {x, x};
                    p2[t*8 + m*4 + 0] = __builtin_elementwise_fma(xx, w0lo, p2[t*8 + m*4 + 0]);
                    p2[t*8 + m*4 + 1] = __builtin_elementwise_fma(xx, w0hi, p2[t*8 + m*4 + 1]);
                    p2[t*8 + m*4 + 2] = __builtin_elementwise_fma(xx, w1lo, p2[t*8 + m*4 + 2]);
                    p2[t*8 + m*4 + 3] = __builtin_elementwise_fma(xx, w1hi, p2[t*8 + m*4 + 3]);
                }
            }
        }

        // write next super's W into the other buffer; one barrier per super
        if (more) {
            const int ob = (cur ^ 1) * 1024;
#pragma unroll
            for (int k = 0; k < 4; ++k) sW4[ob + k * 256 + tid] = sreg[k];
            __syncthreads();
        }
    }

    // ---- 5-step compacting butterfly over 32 values + cross-half add ----
    // value j: t=j>>4, o8=(j>>1)&7, m=j&1. After 5 LSB-first steps lane L
    // holds q[0] = value (L&31) summed over its 32-lane half; the xor-32 add
    // completes the 64-lane sum. Lanes 32-63 mirror lanes 0-31.
    float q[32];
#pragma unroll
    for (int j = 0; j < 32; ++j) {
        const int t = j >> 4, m = j & 1, e = (j >> 2) & 3, el = (j >> 1) & 1;
        q[j] = p2[t*8 + m*4 + e][el];
    }
#pragma unroll
    for (int s = 0; s < 5; ++s) {
        const int mm = 1 << s;
        const bool hi = (lane & mm) != 0;
        const int n = 32 >> (s + 1);
#pragma unroll
        for (int j = 0; j < n; ++j) {
            float a  = q[2 * j];
            float b  = q[2 * j + 1];
            float ta = __shfl_xor(a, mm, 64);
            float tb = __shfl_xor(b, mm, 64);
            q[j] = hi ? (b + tb) : (a + ta);
        }
    }
    const float r0 = q[0] + __shfl_xor(q[0], 32, 64);

    // Epilogue (verified map): lane L<32 -> token t0+(L>>4), expert (L>>1)&7,
    // matrix L&1. (lane>>4)&1 clamps mirror lanes to valid tokens (OOB guard).
    const int  o         = (lane >> 1) & 7;
    const bool noiseLane = (role != 0);
    const int  tok       = t0 + ((lane >> 4) & 1);
    const float bias     = noiseLane ? bn[o] : bw[o];

    const float val = r0 + bias;                // logit (role 0) or noise-logit (role 1)
    const float sp  = softplus_f(val);
    const float spN = __shfl_xor(sp, 1, 64);    // logit lane <- partner's softplus
    const float ev  = eps[(size_t)tok * NEXP + o];
    const float noisy = val + ev * spN;         // meaningful on logit lanes

    // argmax over the 8 logit lanes (same token, role 0): masks {2,4,8}
    float v0 = noisy; int i0 = o;
#pragma unroll
    for (int m = 2; m <= 8; m <<= 1) {
        float ov = __shfl_xor(v0, m, 64);
        int   oi = __shfl_xor(i0, m, 64);
        bool take = (ov > v0) || (ov == v0 && oi < i0);
        v0 = take ? ov : v0;
        i0 = take ? oi : i0;
    }
    // second argmax (exclude i0)
    float v1 = (o == i0) ? -INFINITY : noisy; int i1 = o;
#pragma unroll
    for (int m = 2; m <= 8; m <<= 1) {
        float ov = __shfl_xor(v1, m, 64);
        int   oi = __shfl_xor(i1, m, 64);
        bool take = (ov > v1) || (ov == v1 && oi < i1);
        v1 = take ? ov : v1;
        i1 = take ? oi : i1;
    }
    // full softmax over 8 experts
    const float ex = expf(noisy - v0);
    float ssum = ex;
#pragma unroll
    for (int m = 2; m <= 8; m <<= 1) ssum += __shfl_xor(ssum, m, 64);
    const float fullv = ex / ssum;
    // sparse softmax over the top-2 (others exactly 0)
    const float dd  = expf(v1 - v0);
    const float den = 1.0f + dd;
    const float sparsev = (o == i0) ? (1.0f / den)
                        : (o == i1) ? (dd / den) : 0.0f;

    if (!noiseLane && lane < 32) {
        out_sparse[(size_t)tok * NEXP + o] = sparsev;
        out_full  [(size_t)tok * NEXP + o] = fullv;
        if (o == 0) {
            out_ix[(size_t)tok * 2]     = (float)i0;
            out_ix[(size_t)tok * 2 + 1] = (float)i1;
        }
    }
}

extern "C" void kernel_launch(void* const* d_in, const int* in_sizes, int n_in,
                              void* d_out, int out_size, void* d_ws, size_t ws_size,
                              hipStream_t stream) {
    const float* h   = (const float*)d_in[0];
    const float* Ww  = (const float*)d_in[1];
    const float* bw  = (const float*)d_in[2];
    const float* Wn  = (const float*)d_in[3];
    const float* bn  = (const float*)d_in[4];
    const float* eps = (const float*)d_in[5];
    // d_in[6] = top_k (always 2 for this problem)

    float* out_sparse = (float*)d_out;                         // [T, 8]
    float* out_ix     = out_sparse + (size_t)NTOK * NEXP;      // [T, 2] (as float)
    float* out_full   = out_ix + (size_t)NTOK * 2;             // [T, 8]

    const int grid = NTOK / (TT * WPB);  // 4096 blocks x 256 threads
    noisy_topk_router<<<grid, 256, 0, stream>>>(h, Ww, bw, Wn, bn, eps,
                                                out_sparse, out_ix, out_full);
}